// Round 9
// baseline (221.877 us; speedup 1.0000x reference)
//
#include <hip/hip_runtime.h>

// out[n,i,j] = sum_k x[n,i,k] * w[i,j,k] + b[i,j]   (N=128, D=512)
// One block per i; 32 chunks of 16 j-rows at full K.
// W: glds f32 -> 2x32KB ring, wave w owns rows {2w,2w+1}. Each wave converts
// ITS OWN rows to bf16 IN PLACE (low 2KB of its 4KB region) late in body(c)
// for chunk c+1 -> no cross-wave hazard, no extra LDS, ONE barrier per chunk.
// MFMA reads scattered-bf16 layout: row r at (r>>1)*4096 + (r&1)*1024, koff
// XOR-swizzled by ((r&7)<<4). Counted vmcnt(5); glds(c+2) after the barrier.
// X loaded direct global->registers (no staging, no prologue barriers).

#define Dd 512
#define DD (512 * 512)

typedef __attribute__((ext_vector_type(8))) short bf16x8;
typedef __attribute__((ext_vector_type(4))) short bf16x4;
typedef __attribute__((ext_vector_type(4))) float f32x4;

__device__ __forceinline__ short f2bf(float f) {
    unsigned u = __builtin_bit_cast(unsigned, f);
    u += 0x7FFFu + ((u >> 16) & 1u);      // RNE
    return (short)(u >> 16);
}

__device__ __forceinline__ bf16x8 cvt8(float4 a, float4 b) {
    bf16x8 h;
    h[0] = f2bf(a.x); h[1] = f2bf(a.y); h[2] = f2bf(a.z); h[3] = f2bf(a.w);
    h[4] = f2bf(b.x); h[5] = f2bf(b.y); h[6] = f2bf(b.z); h[7] = f2bf(b.w);
    return h;
}

__device__ __forceinline__ void glds16(const float* g, float* l) {
    __builtin_amdgcn_global_load_lds(
        (const __attribute__((address_space(1))) void*)g,
        (__attribute__((address_space(3))) void*)l, 16, 0, 0);
}

__global__ __launch_bounds__(512, 4)
void linear3d_kernel(const float* __restrict__ x,
                     const float* __restrict__ w,
                     const float* __restrict__ b,
                     float* __restrict__ out) {
    const int i    = blockIdx.x;
    const int tid  = threadIdx.x;
    const int lane = tid & 63;
    const int wid  = tid >> 6;            // wave owns n-rows [wid*16,+16) and W-rows {2wid,2wid+1}
    const int row16 = lane & 15;
    const int cg    = lane >> 4;

    __shared__ float f32r[2][8192];       // 64 KB ring (glds dst; wave-private 4KB regions)

    const float* xi = x + (size_t)i * Dd;         // x[n,i,k] = xi[n*DD + k]
    const float* wi = w + (size_t)i * DD;         // w[i,j,k] = wi[j*Dd + k]

    // wave's rows of chunk c are global floats [c*8192 + wid*1024, +1024) - contiguous
#define WGLDS(cidx, slot) do {                                                 \
    const float* gsrc_ = wi + (size_t)(cidx) * 8192 + wid * 1024;              \
    float* ldst_ = &f32r[slot][wid * 1024];                                    \
    _Pragma("unroll")                                                          \
    for (int q = 0; q < 4; ++q)                                                \
        glds16(gsrc_ + q * 256 + lane * 4, ldst_ + q * 256);                   \
} while (0)

    // in-place convert of this wave's 2 rows of chunk in SLOT: f32 [wid*4096,
    // +4096) -> bf16 [wid*4096, +2048), scattered layout + XOR swizzle.
#define CONVERT(SLOT) do {                                                     \
    const float* fb_ = &f32r[SLOT][wid * 1024];                                \
    float4 c0_ = *(const float4*)(fb_ +   0 + lane * 4);                       \
    float4 c1_ = *(const float4*)(fb_ + 256 + lane * 4);                       \
    float4 c2_ = *(const float4*)(fb_ + 512 + lane * 4);                       \
    float4 c3_ = *(const float4*)(fb_ + 768 + lane * 4);                       \
    char* wb_ = (char*)&f32r[SLOT][0] + wid * 4096;                            \
    const int sz0_ = ((2 * wid) & 7) << 4;                                     \
    const int sz1_ = sz0_ | 16;                                                \
    bf16x4 h0_ = { f2bf(c0_.x), f2bf(c0_.y), f2bf(c0_.z), f2bf(c0_.w) };       \
    bf16x4 h1_ = { f2bf(c1_.x), f2bf(c1_.y), f2bf(c1_.z), f2bf(c1_.w) };       \
    bf16x4 h2_ = { f2bf(c2_.x), f2bf(c2_.y), f2bf(c2_.z), f2bf(c2_.w) };       \
    bf16x4 h3_ = { f2bf(c3_.x), f2bf(c3_.y), f2bf(c3_.z), f2bf(c3_.w) };       \
    *(bf16x4*)(wb_ + ((      lane * 8) ^ sz0_)) = h0_;                         \
    *(bf16x4*)(wb_ + ((512 + lane * 8) ^ sz0_)) = h1_;                         \
    *(bf16x4*)(wb_ + 1024 + ((      lane * 8) ^ sz1_)) = h2_;                  \
    *(bf16x4*)(wb_ + 1024 + ((512 + lane * 8) ^ sz1_)) = h3_;                  \
} while (0)

    // ---- prologue: bias(0), W chunks 0,1 in flight, X direct to registers
    float bias_cur = b[i * Dd + row16];
    WGLDS(0, 0);
    WGLDS(1, 1);

    const float* xrow = xi + (size_t)(wid * 16 + row16) * DD + cg * 8;
    float4 pa0 = *(const float4*)(xrow + 0);
    float4 pa1 = *(const float4*)(xrow + 4);
    float4 pa2 = *(const float4*)(xrow + 32);
    float4 pa3 = *(const float4*)(xrow + 36);

    bf16x8 xf[16];
    #pragma unroll
    for (int r = 0; r < 8; ++r) {
        float4 pb0, pb1, pb2, pb3;
        if (r < 7) {
            const float* xb = xrow + (2 * r + 2) * 32;
            pb0 = *(const float4*)(xb + 0);
            pb1 = *(const float4*)(xb + 4);
            pb2 = *(const float4*)(xb + 32);
            pb3 = *(const float4*)(xb + 36);
        }
        if (r < 7) asm volatile("s_waitcnt vmcnt(4)" ::: "memory");
        else       asm volatile("s_waitcnt vmcnt(0)" ::: "memory");
        __builtin_amdgcn_sched_barrier(0);
        xf[2 * r]     = cvt8(pa0, pa1);
        xf[2 * r + 1] = cvt8(pa2, pa3);
        pa0 = pb0; pa1 = pb1; pa2 = pb2; pa3 = pb3;
    }

    CONVERT(0);                           // glds(0) retired by the vmcnt(0) above
    asm volatile("s_waitcnt lgkmcnt(0)" ::: "memory");
    __builtin_amdgcn_s_barrier();
    __builtin_amdgcn_sched_barrier(0);

    const int base_r = (row16 >> 1) * 4096 + (row16 & 1) * 1024;
    const int swz_r  = (row16 & 7) << 4;
    const int kx     = cg * 16;

    // Body(c): [bias(c+1)] [16 MFMA from slot c&1 bf16] [4 stores]
    // [vmcnt(5): glds(c+1) retired (newer = bias + st x4); CONVERT(c+1) into
    //  slot (c+1)&1 low bytes, wave-local] [lgkm0; s_barrier]
    // [glds(c+2) -> slot c&1].  One barrier/chunk; no vmcnt(0) in loop.
#define BODY(c, DO_CONV, DO_GLDS, DO_BIAS) do {                                \
    float biasN_ = bias_cur;                                                   \
    if (DO_BIAS) biasN_ = b[i * Dd + ((c) + 1) * 16 + row16];                  \
    const char* buf_ = (const char*)&f32r[(c) & 1][0];                         \
    f32x4 accA = {0.f, 0.f, 0.f, 0.f}, accB = {0.f, 0.f, 0.f, 0.f};            \
    _Pragma("unroll")                                                          \
    for (int s = 0; s < 16; s += 2) {                                          \
        bf16x8 wfA_ = *(const bf16x8*)(buf_ + base_r + ((s * 64 + kx) ^ swz_r)); \
        bf16x8 wfB_ = *(const bf16x8*)(buf_ + base_r + (((s + 1) * 64 + kx) ^ swz_r)); \
        accA = __builtin_amdgcn_mfma_f32_16x16x32_bf16(xf[s], wfA_, accA, 0, 0, 0);     \
        accB = __builtin_amdgcn_mfma_f32_16x16x32_bf16(xf[s + 1], wfB_, accB, 0, 0, 0); \
    }                                                                          \
    { int j_ = (c) * 16 + row16;                                               \
      _Pragma("unroll")                                                        \
      for (int r_ = 0; r_ < 4; ++r_) {                                         \
          int n_ = wid * 16 + cg * 4 + r_;                                     \
          out[(size_t)n_ * DD + (size_t)i * Dd + j_] =                         \
              accA[r_] + accB[r_] + bias_cur;                                  \
      } }                                                                      \
    if (DO_CONV) {                                                             \
        asm volatile("s_waitcnt vmcnt(5)" ::: "memory");                       \
        __builtin_amdgcn_sched_barrier(0);                                     \
        CONVERT(((c) + 1) & 1);                                                \
        asm volatile("s_waitcnt lgkmcnt(0)" ::: "memory");                     \
        __builtin_amdgcn_s_barrier();                                          \
        __builtin_amdgcn_sched_barrier(0);                                     \
        if (DO_GLDS) {                                                         \
            WGLDS((c) + 2, (c) & 1);                                           \
            __builtin_amdgcn_sched_barrier(0);                                 \
        }                                                                      \
    }                                                                          \
    bias_cur = biasN_;                                                         \
} while (0)

    BODY(0, true, true, true);
    #pragma unroll 1
    for (int c = 1; c <= 29; ++c)
        BODY(c, true, true, true);
    BODY(30, true, false, true);          // glds(32) doesn't exist
    BODY(31, false, false, false);        // bare tail: MFMA + stores only

#undef BODY
#undef CONVERT
#undef WGLDS
}

extern "C" void kernel_launch(void* const* d_in, const int* in_sizes, int n_in,
                              void* d_out, int out_size, void* d_ws, size_t ws_size,
                              hipStream_t stream) {
    const float* x = (const float*)d_in[0];
    const float* w = (const float*)d_in[1];
    const float* b = (const float*)d_in[2];
    float* out = (float*)d_out;
    linear3d_kernel<<<dim3(Dd), dim3(512), 0, stream>>>(x, w, b, out);
}

// Round 10
// 191.009 us; speedup vs baseline: 1.1616x; 1.1616x over previous
//
#include <hip/hip_runtime.h>

// out[n,i,j] = sum_k x[n,i,k] * w[i,j,k] + b[i,j]   (N=128, D=512)
// R4 structure (best measured: 184.8us) with ONE change: barrier-free
// wave-local X staging (was 17 block barriers). Main loop identical to R4.

#define Dd 512
#define DD (512 * 512)
#define CHUNK 16
#define NCHUNK 32

typedef __attribute__((ext_vector_type(8))) short bf16x8;
typedef __attribute__((ext_vector_type(4))) short bf16x4;
typedef __attribute__((ext_vector_type(4))) float f32x4;

__device__ __forceinline__ short f2bf(float f) {
    unsigned u = __builtin_bit_cast(unsigned, f);
    u += 0x7FFFu + ((u >> 16) & 1u);      // RNE
    return (short)(u >> 16);
}

__device__ __forceinline__ bf16x8 cvt8(float4 a, float4 b) {
    bf16x8 h;
    h[0] = f2bf(a.x); h[1] = f2bf(a.y); h[2] = f2bf(a.z); h[3] = f2bf(a.w);
    h[4] = f2bf(b.x); h[5] = f2bf(b.y); h[6] = f2bf(b.z); h[7] = f2bf(b.w);
    return h;
}

__device__ __forceinline__ void glds16(const float* g, float* l) {
    __builtin_amdgcn_global_load_lds(
        (const __attribute__((address_space(1))) void*)g,
        (__attribute__((address_space(3))) void*)l, 16, 0, 0);
}

__global__ __launch_bounds__(512, 4)
void linear3d_kernel(const float* __restrict__ x,
                     const float* __restrict__ w,
                     const float* __restrict__ b,
                     float* __restrict__ out) {
    const int i    = blockIdx.x;
    const int tid  = threadIdx.x;
    const int lane = tid & 63;
    const int wid  = tid >> 6;            // wave owns n-rows [wid*16, +16)
    const int row16 = lane & 15;
    const int cg    = lane >> 4;

    __shared__ float f32s[CHUNK * Dd];    // 32 KB f32 W chunk (glds target)
    __shared__ short b16[2][CHUNK * Dd];  // 2 x 16 KB swizzled bf16 W chunk
    __shared__ float ldsb[Dd];            // bias row

    const float* xi = x + (size_t)i * Dd;         // x[n,i,k] = xi[n*DD + k]
    const float* wi = w + (size_t)i * DD;         // w[i,j,k] = wi[j*Dd + k]

    ldsb[tid] = b[i * Dd + tid];

    // ---- issue W chunk 0 -> f32s (latency hidden under X staging)
    #pragma unroll
    for (int q = 0; q < 4; ++q)
        glds16(wi + (size_t)(wid * 256 + q * 64 + lane) * 4,
               &f32s[(wid * 256 + q * 64) * 4]);

    // ---- wave-local X staging: NO block barriers. Wave wid stages its rows
    // n = wid*16 + r through a private 4KB scratch ring (4 x 1KB bf16-row
    // slots) in the b16 area (8 waves x 4KB = 32KB). Dense 2KB global row
    // reads; compiler pipelines rows via normal wave-local dependencies.
    bf16x8 xf[16];
    {
        char* ws = (char*)&b16[0][0] + wid * 4096;
        #pragma unroll
        for (int r = 0; r < 16; ++r) {
            const float* xr = xi + (size_t)(wid * 16 + r) * DD;
            float4 va = *(const float4*)(xr + lane * 8);
            float4 vb = *(const float4*)(xr + lane * 8 + 4);
            char* slot = ws + (r & 3) * 1024;
            bf16x8 hv = cvt8(va, vb);
            *(bf16x8*)(slot + lane * 16) = hv;    // row r, linear in k
            if (row16 == r) {                     // 4 owning lanes read back
                #pragma unroll
                for (int s = 0; s < 16; ++s)
                    xf[s] = *(const bf16x8*)(slot + s * 64 + cg * 16);
            }
        }
    }

    __syncthreads();   // staging reads done; glds(0) drained & visible

    // ---- convert W0: f32s -> b16[0] (R4 verbatim)
    #pragma unroll
    for (int p = 0; p < 4; ++p) {
        int idx4 = tid + p * 512;
        int row = idx4 >> 7, c4 = idx4 & 127;
        float4 v = *(const float4*)(f32s + idx4 * 4);
        bf16x4 h = { f2bf(v.x), f2bf(v.y), f2bf(v.z), f2bf(v.w) };
        int byte = (row * 1024 + c4 * 8) ^ ((row & 7) << 4);
        *(bf16x4*)((char*)&b16[0][0] + byte) = h;
    }
    asm volatile("s_waitcnt lgkmcnt(0)" ::: "memory");
    __builtin_amdgcn_s_barrier();

    // ---- issue W chunk 1 -> f32s
    #pragma unroll
    for (int q = 0; q < 4; ++q)
        glds16(wi + (size_t)(CHUNK * Dd) + (size_t)(wid * 256 + q * 64 + lane) * 4,
               &f32s[(wid * 256 + q * 64) * 4]);

    const int nb = wid * 16;
    float* outbase = out + (size_t)i * Dd;

    // ---- main loop: R4 VERBATIM
    for (int c = 0; c < NCHUNK; ++c) {
        const char* buf = (const char*)&b16[c & 1][0];
        f32x4 acc = {0.f, 0.f, 0.f, 0.f};
        #pragma unroll
        for (int s = 0; s < 16; ++s) {
            int byte = (row16 * 1024 + s * 64 + cg * 16) ^ ((row16 & 7) << 4);
            bf16x8 wf = *(const bf16x8*)(buf + byte);
            acc = __builtin_amdgcn_mfma_f32_16x16x32_bf16(xf[s], wf, acc, 0, 0, 0);
        }
        float bias = ldsb[c * 16 + row16];
        #pragma unroll
        for (int r = 0; r < 4; ++r) {
            int n = nb + cg * 4 + r;
            outbase[(size_t)n * DD + c * CHUNK + row16] = acc[r] + bias;
        }

        if (c + 1 < NCHUNK) {
            asm volatile("s_waitcnt lgkmcnt(0) vmcnt(4)" ::: "memory");
            __builtin_amdgcn_s_barrier();

            char* dstb = (char*)&b16[(c + 1) & 1][0];
            #pragma unroll
            for (int p = 0; p < 4; ++p) {
                int idx4 = tid + p * 512;
                int row = idx4 >> 7, cu = idx4 & 127;
                float4 v = *(const float4*)(f32s + idx4 * 4);
                bf16x4 h = { f2bf(v.x), f2bf(v.y), f2bf(v.z), f2bf(v.w) };
                int byte = (row * 1024 + cu * 8) ^ ((row & 7) << 4);
                *(bf16x4*)(dstb + byte) = h;
            }
            asm volatile("s_waitcnt lgkmcnt(0)" ::: "memory");
            __builtin_amdgcn_s_barrier();

            if (c + 2 < NCHUNK) {
                const float* src = wi + (size_t)(c + 2) * (CHUNK * Dd);
                #pragma unroll
                for (int q = 0; q < 4; ++q)
                    glds16(src + (size_t)(wid * 256 + q * 64 + lane) * 4,
                           &f32s[(wid * 256 + q * 64) * 4]);
            }
        }
    }
}

extern "C" void kernel_launch(void* const* d_in, const int* in_sizes, int n_in,
                              void* d_out, int out_size, void* d_ws, size_t ws_size,
                              hipStream_t stream) {
    const float* x = (const float*)d_in[0];
    const float* w = (const float*)d_in[1];
    const float* b = (const float*)d_in[2];
    float* out = (float*)d_out;
    linear3d_kernel<<<dim3(Dd), dim3(512), 0, stream>>>(x, w, b, out);
}